// Round 6
// baseline (313.836 us; speedup 1.0000x reference)
//
#include <hip/hip_runtime.h>
#include <cstdint>
#include <cstddef>

typedef unsigned short ushort_t;
typedef __bf16 bf16x8 __attribute__((ext_vector_type(8)));
typedef float f32x4 __attribute__((ext_vector_type(4)));
typedef unsigned short u16x8 __attribute__((ext_vector_type(8)));
typedef short s16x8 __attribute__((ext_vector_type(8)));

__device__ __forceinline__ ushort_t f2bf(float f) {
    unsigned u = __builtin_bit_cast(unsigned, f);
    unsigned r = (u + 0x7FFFu + ((u >> 16) & 1u)) >> 16;
    return (ushort_t)r;
}
__device__ __forceinline__ float bf2f(ushort_t h) {
    unsigned u = ((unsigned)h) << 16;
    return __builtin_bit_cast(float, u);
}

#define FFT_N 2048
__device__ __forceinline__ int PADi(int i) { return i + (i >> 4); }

__device__ __forceinline__ float2 cmul(float2 u, float2 w) {
    return make_float2(u.x * w.x - u.y * w.y, u.x * w.y + u.y * w.x);
}
__device__ __forceinline__ float2 cadd(float2 a, float2 b) { return make_float2(a.x + b.x, a.y + b.y); }
__device__ __forceinline__ float2 csub(float2 a, float2 b) { return make_float2(a.x - b.x, a.y - b.y); }

// DIF radix-4 with precomputed (w, w^2, w^3); slot placement with branch
// 1<->2 swap -- math verbatim from verified round-4 dif4.
__device__ __forceinline__ void dif4t(float2* v, float2 w, float2 w2, float2 w3) {
    float2 t0 = cadd(v[0], v[2]);
    float2 t1 = csub(v[0], v[2]);
    float2 t2 = cadd(v[1], v[3]);
    float2 t3 = csub(v[1], v[3]);
    v[0] = cadd(t0, t2);
    v[1] = cmul(csub(t0, t2), w2);
    float2 b1 = make_float2(t1.x + t3.y, t1.y - t3.x);
    v[2] = cmul(b1, w);
    float2 b3 = make_float2(t1.x - t3.y, t1.y + t3.x);
    v[3] = cmul(b3, w3);
}

// DIT radix-4 with precomputed (w, w^2, w^3); natural slot placement --
// math verbatim from verified round-4 dit4 (v1*w^2, v2*w, v3*w^3).
__device__ __forceinline__ void dit4t(float2* v, float2 w, float2 w2, float2 w3) {
    float2 t1 = cmul(v[1], w2);
    float2 t2 = cmul(v[2], w);
    float2 t3 = cmul(v[3], w3);
    float2 sA = cadd(v[0], t1);
    float2 sB = csub(v[0], t1);
    float2 sC = cadd(t2, t3);
    float2 u  = csub(t2, t3);
    v[0] = cadd(sA, sC);
    v[1] = make_float2(sB.x + u.y, sB.y - u.x);
    v[2] = csub(sA, sC);
    v[3] = make_float2(sB.x - u.y, sB.y + u.x);
}

// ---------------------------------------------------------------------------
// twiddle init: triplets (w,w^2,w^3) for level tables (341 entries) + T11.
// twg layout: [0..1023) = 341 triplets; [1023..2047) = T11 singles.
// ---------------------------------------------------------------------------
__global__ __launch_bounds__(256) void twinit_kernel(float2* __restrict__ twg)
{
    int idx = blockIdx.x * 256 + threadIdx.x;
    if (idx >= 1365) return;
    float ang;
    if (idx < 341) {
        int m, p;
        if (idx >= 85)      { m = 4; p = idx - 85; }
        else if (idx >= 21) { m = 3; p = idx - 21; }
        else if (idx >= 5)  { m = 2; p = idx - 5; }
        else if (idx >= 1)  { m = 1; p = idx - 1; }
        else                { m = 0; p = 0; }
        ang = -6.28318530717958647692f * (float)p / (float)(4 << (2 * m));
        float s, co;
        __sincosf(ang, &s, &co);
        float2 w = make_float2(co, s);
        float2 w2 = make_float2(w.x * w.x - w.y * w.y, 2.0f * w.x * w.y);
        float2 w3 = cmul(w2, w);
        twg[idx * 3]     = w;
        twg[idx * 3 + 1] = w2;
        twg[idx * 3 + 2] = w3;
    } else {
        ang = -3.14159265358979323846f * (float)(idx - 341) / 1024.0f;
        float s, co;
        __sincosf(ang, &s, &co);
        twg[1023 + (idx - 341)] = make_float2(co, s);
    }
}

// ---------------------------------------------------------------------------
// Kernel A: Hilbert -> unit-phasor z. 4 rows per block (2 packed row-pairs),
// 128 threads per packed FFT. P = x0 + i*x1 -> Z = DIF-fft(P) (bitrev order)
// -> conj(Q) where Q = -i*Z (k in [1,1023]), 0 (k=0,1024), +i*Z (k>=1025)
// -> w = DIT-fft -> H0 = w.x/N, H1 = -w.y/N -> z_j = norm(N*x_j + i*H_j).
// ---------------------------------------------------------------------------
__global__ __launch_bounds__(256, 4) void hilbert_kernel(
    const float* __restrict__ x, ushort_t* __restrict__ zre,
    ushort_t* __restrict__ zim, const float2* __restrict__ twg, int b0)
{
    __shared__ float2 cA[2][2176];
    const int tid = threadIdx.x;
    const int pl = tid >> 7;                     // packed-pair slot in block
    const int t = tid & 127;
    const int pairIdx = blockIdx.x * 2 + pl;     // local row-pair in chunk
    const int row0 = pairIdx * 2;                // local rows row0, row0+1
    const size_t grow = (size_t)(b0 * 128) + row0;
    const float* x0r = x + grow * FFT_N;
    const float* x1r = x0r + FFT_N;
    float2* c = cA[pl];
    const float2* trip = twg;                    // 341 triplets
    const float2* T11  = twg + 1023;             // 1024 singles
    const float2* tb1t = trip + 3;               // level bases *3
    const float2* tb2t = trip + 15;
    const float2* tb3t = trip + 63;
    const float2* tb4t = trip + 255;
    const float2 one = make_float2(1.0f, 0.0f);

    float2 xa[2][4], xb[2][4];                   // P[n], P[n+1024] saved

    // ---- DIF pass 1: load packed, r2 (T11), dif4 m=4 (tb4 triplet) ----
#pragma unroll
    for (int it = 0; it < 2; ++it) {
        int i = t + it * 128;                    // [0,256)
        float2 v[4][2];
#pragma unroll
        for (int a = 0; a < 4; ++a) {
            int n = i + 256 * a;
            float2 Pn = make_float2(x0r[n], x1r[n]);
            float2 Pm = make_float2(x0r[n + 1024], x1r[n + 1024]);
            xa[it][a] = Pn; xb[it][a] = Pm;
            float2 w = T11[n];
            v[a][0] = cadd(Pn, Pm);
            v[a][1] = cmul(csub(Pn, Pm), w);
        }
        float2 w4 = tb4t[i * 3], w42 = tb4t[i * 3 + 1], w43 = tb4t[i * 3 + 2];
#pragma unroll
        for (int cc = 0; cc < 2; ++cc) {
            float2 u[4];
#pragma unroll
            for (int a = 0; a < 4; ++a) u[a] = v[a][cc];
            dif4t(u, w4, w42, w43);
            int base = PADi(i) + 1088 * cc;
#pragma unroll
            for (int s = 0; s < 4; ++s) c[base + 272 * s] = u[s];
        }
    }
    __syncthreads();

    // ---- DIF pass 2: m=3 (tb3[p+16a]), m=2 (tb2[p]) ----
    {
        int p = t & 15, g = t >> 4;
        int base = 272 * g + p;
        float2 v[4][4];
#pragma unroll
        for (int a = 0; a < 4; ++a)
#pragma unroll
            for (int b = 0; b < 4; ++b) v[a][b] = c[base + 17 * a + 68 * b];
#pragma unroll
        for (int a = 0; a < 4; ++a) {
            int j = (p + 16 * a) * 3;
            float2 u[4];
#pragma unroll
            for (int b = 0; b < 4; ++b) u[b] = v[a][b];
            dif4t(u, tb3t[j], tb3t[j + 1], tb3t[j + 2]);
#pragma unroll
            for (int b = 0; b < 4; ++b) v[a][b] = u[b];
        }
        float2 w2p = tb2t[p * 3], w2p2 = tb2t[p * 3 + 1], w2p3 = tb2t[p * 3 + 2];
#pragma unroll
        for (int b = 0; b < 4; ++b) {
            float2 u[4];
#pragma unroll
            for (int a = 0; a < 4; ++a) u[a] = v[a][b];
            dif4t(u, w2p, w2p2, w2p3);
#pragma unroll
            for (int a = 0; a < 4; ++a) v[a][b] = u[a];
        }
#pragma unroll
        for (int a = 0; a < 4; ++a)
#pragma unroll
            for (int b = 0; b < 4; ++b) c[base + 17 * a + 68 * b] = v[a][b];
    }
    __syncthreads();

    // ---- DIF pass 3: m=1 (tb1[a]), m=0 (w=1); fused Q-mask (sign/swap) ----
    {
        int g = t;
        int base = 17 * g;
        float2 v[4][4];                          // [b][a], idx = 16g+4b+a
#pragma unroll
        for (int b = 0; b < 4; ++b)
#pragma unroll
            for (int a = 0; a < 4; ++a) v[b][a] = c[base + 4 * b + a];
#pragma unroll
        for (int a = 0; a < 4; ++a) {
            int j = a * 3;
            float2 u[4];
#pragma unroll
            for (int b = 0; b < 4; ++b) u[b] = v[b][a];
            dif4t(u, tb1t[j], tb1t[j + 1], tb1t[j + 2]);
#pragma unroll
            for (int b = 0; b < 4; ++b) v[b][a] = u[b];
        }
#pragma unroll
        for (int b = 0; b < 4; ++b) dif4t(v[b], one, one, one);
        // conj(Q): k in [1,1023] -> (v.y, v.x); k in {0,1024} -> 0;
        //          k >= 1025    -> (-v.y, -v.x)
#pragma unroll
        for (int b = 0; b < 4; ++b)
#pragma unroll
            for (int a = 0; a < 4; ++a) {
                int idx = 16 * g + 4 * b + a;
                int k = __brev((unsigned)idx) >> 21;
                float s = (k == 0 || k == 1024) ? 0.0f : (k < 1024 ? 1.0f : -1.0f);
                float2 w = v[b][a];
                c[base + 4 * b + a] = make_float2(s * w.y, s * w.x);
            }
    }
    __syncthreads();

    // ---- DIT pass 1: m=0 (w=1), m=1 (tb1[a]) ----
    {
        int g = t;
        int base = 17 * g;
        float2 v[4][4];
#pragma unroll
        for (int b = 0; b < 4; ++b)
#pragma unroll
            for (int a = 0; a < 4; ++a) v[b][a] = c[base + 4 * b + a];
#pragma unroll
        for (int b = 0; b < 4; ++b) dit4t(v[b], one, one, one);
#pragma unroll
        for (int a = 0; a < 4; ++a) {
            int j = a * 3;
            float2 u[4];
#pragma unroll
            for (int b = 0; b < 4; ++b) u[b] = v[b][a];
            dit4t(u, tb1t[j], tb1t[j + 1], tb1t[j + 2]);
#pragma unroll
            for (int b = 0; b < 4; ++b) v[b][a] = u[b];
        }
#pragma unroll
        for (int b = 0; b < 4; ++b)
#pragma unroll
            for (int a = 0; a < 4; ++a) c[base + 4 * b + a] = v[b][a];
    }
    __syncthreads();

    // ---- DIT pass 2: m=2 (tb2[p]), m=3 (tb3[p+16a]) ----
    {
        int p = t & 15, g = t >> 4;
        int base = 272 * g + p;
        float2 v[4][4];
#pragma unroll
        for (int a = 0; a < 4; ++a)
#pragma unroll
            for (int b = 0; b < 4; ++b) v[a][b] = c[base + 17 * a + 68 * b];
        float2 w2p = tb2t[p * 3], w2p2 = tb2t[p * 3 + 1], w2p3 = tb2t[p * 3 + 2];
#pragma unroll
        for (int b = 0; b < 4; ++b) {
            float2 u[4];
#pragma unroll
            for (int a = 0; a < 4; ++a) u[a] = v[a][b];
            dit4t(u, w2p, w2p2, w2p3);
#pragma unroll
            for (int a = 0; a < 4; ++a) v[a][b] = u[a];
        }
#pragma unroll
        for (int a = 0; a < 4; ++a) {
            int j = (p + 16 * a) * 3;
            float2 u[4];
#pragma unroll
            for (int b = 0; b < 4; ++b) u[b] = v[a][b];
            dit4t(u, tb3t[j], tb3t[j + 1], tb3t[j + 2]);
#pragma unroll
            for (int b = 0; b < 4; ++b) v[a][b] = u[b];
        }
#pragma unroll
        for (int a = 0; a < 4; ++a)
#pragma unroll
            for (int b = 0; b < 4; ++b) c[base + 17 * a + 68 * b] = v[a][b];
    }
    __syncthreads();

    // ---- DIT pass 3: m=4 (tb4[i]), r2 (T11); unpack H0,H1, normalize ----
    ushort_t* zr0 = zre + (size_t)row0 * FFT_N;
    ushort_t* zi0 = zim + (size_t)row0 * FFT_N;
    ushort_t* zr1 = zr0 + FFT_N;
    ushort_t* zi1 = zi0 + FFT_N;
#pragma unroll
    for (int it = 0; it < 2; ++it) {
        int i = t + it * 128;
        float2 v[4][2];
#pragma unroll
        for (int cc = 0; cc < 2; ++cc) {
            int base = PADi(i) + 1088 * cc;
#pragma unroll
            for (int a = 0; a < 4; ++a) v[a][cc] = c[base + 272 * a];
        }
        float2 w4 = tb4t[i * 3], w42 = tb4t[i * 3 + 1], w43 = tb4t[i * 3 + 2];
#pragma unroll
        for (int cc = 0; cc < 2; ++cc) {
            float2 u[4];
#pragma unroll
            for (int a = 0; a < 4; ++a) u[a] = v[a][cc];
            dit4t(u, w4, w42, w43);
#pragma unroll
            for (int a = 0; a < 4; ++a) v[a][cc] = u[a];
        }
#pragma unroll
        for (int a = 0; a < 4; ++a) {
            float2 wa = T11[i + 256 * a];
            float2 tt = cmul(v[a][1], wa);
            float2 e0 = cadd(v[a][0], tt);
            float2 e1 = csub(v[a][0], tt);
            int n0 = i + 256 * a;
#pragma unroll
            for (int h = 0; h < 2; ++h) {
                float2 w = h ? e1 : e0;
                float2 P = h ? xb[it][a] : xa[it][a];
                int n = n0 + 1024 * h;
                float a0 = 2048.0f * P.x, a1 = 2048.0f * P.y;
                float H0 = w.x, H1 = -w.y;
                float m0 = a0 * a0 + H0 * H0;
                float m1 = a1 * a1 + H1 * H1;
                float zr, zi;
                if (m0 < 1e-24f) { zr = 1.0f; zi = 0.0f; }
                else { float inv = rsqrtf(m0); zr = a0 * inv; zi = H0 * inv; }
                zr0[n] = f2bf(zr); zi0[n] = f2bf(zi);
                if (m1 < 1e-24f) { zr = 1.0f; zi = 0.0f; }
                else { float inv = rsqrtf(m1); zr = a1 * inv; zi = H1 * inv; }
                zr1[n] = f2bf(zr); zi1[n] = f2bf(zi);
            }
        }
    }
}

// ---------------------------------------------------------------------------
// Kernel B: conn = |Z Z^H|/T (bf16 MFMA), unchanged.
// ---------------------------------------------------------------------------
__global__ __launch_bounds__(512) void gram_kernel(
    const ushort_t* __restrict__ zre, const ushort_t* __restrict__ zim,
    float* __restrict__ out, int b0)
{
    __shared__ __align__(16) char sm[65536];
    const int tid = threadIdx.x;
    const int bl = blockIdx.x;
    const int b_local = bl >> 1;
    const int half = bl & 1;
    const int b = b0 + b_local;
    const int lane = tid & 63;
    const int w = tid >> 6;
    const int wm = w >> 2, wn = w & 3;
    const size_t zbase = (size_t)b_local * 128 * FFT_N;

    f32x4 accR[2][2], accI[2][2];
    const f32x4 zero4 = {0.f, 0.f, 0.f, 0.f};
#pragma unroll
    for (int mi = 0; mi < 2; ++mi)
#pragma unroll
        for (int nj = 0; nj < 2; ++nj) { accR[mi][nj] = zero4; accI[mi][nj] = zero4; }

    auto stage = [&](int kc, int buf) {
        const int kcol = kc * 64;
#pragma unroll
        for (int it = 0; it < 4; ++it) {
            int cid = it * 512 + tid;
            int p = cid >> 10;
            int rem = cid & 1023;
            int r = rem >> 3;
            int g = rem & 7;
            const ushort_t* src = (p ? zim : zre) + zbase + (size_t)r * FFT_N + kcol + g * 8;
            u16x8 v = *(const u16x8*)src;
            int off = (buf << 15) | (p << 14) | (r << 7) | (g << 4);
            off ^= ((r & 7) << 4);
            *(u16x8*)(sm + off) = v;
        }
    };

    stage(0, 0);
    __syncthreads();
    int buf = 0;
    const int mBase = half * 64 + wm * 32;
    const int nBase = wn * 32;
    for (int kc = 0; kc < 32; ++kc) {
        if (kc + 1 < 32) stage(kc + 1, buf ^ 1);
        const char* base = sm + (buf << 15);
#pragma unroll
        for (int ks = 0; ks < 2; ++ks) {
            bf16x8 aRe[2], aIm[2], bRe[2], bIm[2], nRe[2];
#pragma unroll
            for (int mi = 0; mi < 2; ++mi) {
                int R = mBase + mi * 16 + (lane & 15);
                int off = (R << 7) | (ks << 6) | ((lane >> 4) << 4);
                off ^= ((R & 7) << 4);
                aRe[mi] = *(const bf16x8*)(base + off);
                aIm[mi] = *(const bf16x8*)(base + 16384 + off);
                s16x8 t = __builtin_bit_cast(s16x8, aRe[mi]);
                t ^= (short)0x8000;
                nRe[mi] = __builtin_bit_cast(bf16x8, t);
            }
#pragma unroll
            for (int nj = 0; nj < 2; ++nj) {
                int C = nBase + nj * 16 + (lane & 15);
                int off = (C << 7) | (ks << 6) | ((lane >> 4) << 4);
                off ^= ((C & 7) << 4);
                bRe[nj] = *(const bf16x8*)(base + off);
                bIm[nj] = *(const bf16x8*)(base + 16384 + off);
            }
#pragma unroll
            for (int mi = 0; mi < 2; ++mi)
#pragma unroll
                for (int nj = 0; nj < 2; ++nj) {
                    accR[mi][nj] = __builtin_amdgcn_mfma_f32_16x16x32_bf16(aRe[mi], bRe[nj], accR[mi][nj], 0, 0, 0);
                    accR[mi][nj] = __builtin_amdgcn_mfma_f32_16x16x32_bf16(aIm[mi], bIm[nj], accR[mi][nj], 0, 0, 0);
                    accI[mi][nj] = __builtin_amdgcn_mfma_f32_16x16x32_bf16(aIm[mi], bRe[nj], accI[mi][nj], 0, 0, 0);
                    accI[mi][nj] = __builtin_amdgcn_mfma_f32_16x16x32_bf16(nRe[mi], bIm[nj], accI[mi][nj], 0, 0, 0);
                }
        }
        __syncthreads();
        buf ^= 1;
    }
    float* ob = out + (size_t)b * 16384;
#pragma unroll
    for (int mi = 0; mi < 2; ++mi)
#pragma unroll
        for (int nj = 0; nj < 2; ++nj)
#pragma unroll
            for (int r = 0; r < 4; ++r) {
                int i = mBase + mi * 16 + (lane >> 4) * 4 + r;
                int j = nBase + nj * 16 + (lane & 15);
                float re = accR[mi][nj][r], im = accI[mi][nj][r];
                float v = sqrtf(re * re + im * im) * (1.0f / 2048.0f);
                if (i == j) v = 0.0f;
                ob[i * 128 + j] = v;
            }
}

// ---------------------------------------------------------------------------
// Kernel C (prep): nwT[f][j] = bf16(sum_e emb[j][e]*W1[e][f]); w2t = W2^T bf16
// ---------------------------------------------------------------------------
__global__ __launch_bounds__(256) void prep_kernel(
    const float* __restrict__ emb, const float* __restrict__ W1,
    const float* __restrict__ W2, ushort_t* __restrict__ nwT,
    ushort_t* __restrict__ w2t)
{
    const int tid = threadIdx.x;
    const int bid = blockIdx.x;
    if (bid < 16) {
#pragma unroll
        for (int it = 0; it < 4; ++it) {
            int idx = it * 256 + tid;
            int f = bid * 8 + (idx >> 7);
            int j = idx & 127;
            float acc = 0.0f;
            for (int e = 0; e < 64; ++e) acc += emb[j * 64 + e] * W1[e * 128 + f];
            nwT[f * 128 + j] = f2bf(acc);
        }
    } else {
        int base = (bid - 16) * 4096;
#pragma unroll
        for (int it = 0; it < 16; ++it) {
            int idx = base + it * 256 + tid;
            int f = idx >> 7;
            int g = idx & 127;
            w2t[f * 128 + g] = f2bf(W2[g * 64 + f]);
        }
    }
}

// ---------------------------------------------------------------------------
// Kernel D1 (gcn_a): h1 = relu(conn@nodeW1+b1); t2 = h1@W2 (transposed bf16 out)
// ---------------------------------------------------------------------------
__global__ __launch_bounds__(512) void gcn_a(
    const float* __restrict__ conn, const ushort_t* __restrict__ nwT,
    const ushort_t* __restrict__ w2t, const float* __restrict__ b1,
    ushort_t* __restrict__ t2tg)
{
    __shared__ __align__(16) char cbf[16384];
    __shared__ __align__(16) char h1b[16384];
    const int tid = threadIdx.x;
    const int lane = tid & 63;
    const int w = tid >> 6;
    const int b = blockIdx.x >> 1;
    const int half = blockIdx.x & 1;
    const float* cb = conn + (size_t)b * 16384 + half * 64 * 128;

#pragma unroll
    for (int it = 0; it < 16; ++it) {
        int idx = it * 512 + tid;
        int r = idx >> 7, cc = idx & 127;
        int off = (r * 256 + cc * 2) ^ ((r & 7) << 4);
        *(ushort_t*)(cbf + off) = f2bf(cb[idx]);
    }
    __syncthreads();

    const int nBase = w * 16;
    f32x4 acc[4];
    const f32x4 zero4 = {0.f, 0.f, 0.f, 0.f};
#pragma unroll
    for (int mi = 0; mi < 4; ++mi) acc[mi] = zero4;
#pragma unroll
    for (int ks = 0; ks < 4; ++ks) {
        const bf16x8 bfrag = *(const bf16x8*)((const char*)nwT +
            (nBase + (lane & 15)) * 256 + ks * 64 + ((lane >> 4) << 4));
#pragma unroll
        for (int mi = 0; mi < 4; ++mi) {
            int R = mi * 16 + (lane & 15);
            int off = (R * 256 + ks * 64 + ((lane >> 4) << 4)) ^ ((R & 7) << 4);
            bf16x8 afrag = *(const bf16x8*)(cbf + off);
            acc[mi] = __builtin_amdgcn_mfma_f32_16x16x32_bf16(afrag, bfrag, acc[mi], 0, 0, 0);
        }
    }
    float bias1 = b1[nBase + (lane & 15)];
#pragma unroll
    for (int mi = 0; mi < 4; ++mi)
#pragma unroll
        for (int r = 0; r < 4; ++r) {
            int i = mi * 16 + (lane >> 4) * 4 + r;
            float v = fmaxf(acc[mi][r] + bias1, 0.0f);
            int off = (i * 256 + (nBase + (lane & 15)) * 2) ^ ((i & 7) << 4);
            *(ushort_t*)(h1b + off) = f2bf(v);
        }
    __syncthreads();

    const int wm2 = w >> 2, wn2 = w & 3;
    const int f2Base = wn2 * 16;
    f32x4 acc2[2];
    acc2[0] = zero4; acc2[1] = zero4;
#pragma unroll
    for (int ks = 0; ks < 4; ++ks) {
        const bf16x8 bfrag = *(const bf16x8*)((const char*)w2t +
            (f2Base + (lane & 15)) * 256 + ks * 64 + ((lane >> 4) << 4));
#pragma unroll
        for (int mi = 0; mi < 2; ++mi) {
            int R = wm2 * 32 + mi * 16 + (lane & 15);
            int off = (R * 256 + ks * 64 + ((lane >> 4) << 4)) ^ ((R & 7) << 4);
            bf16x8 afrag = *(const bf16x8*)(h1b + off);
            acc2[mi] = __builtin_amdgcn_mfma_f32_16x16x32_bf16(afrag, bfrag, acc2[mi], 0, 0, 0);
        }
    }
    ushort_t* tb = t2tg + (size_t)b * 8192;
#pragma unroll
    for (int mi = 0; mi < 2; ++mi)
#pragma unroll
        for (int r = 0; r < 4; ++r) {
            int i = wm2 * 32 + mi * 16 + (lane >> 4) * 4 + r;
            int f = f2Base + (lane & 15);
            tb[f * 128 + half * 64 + i] = f2bf(acc2[mi][r]);
        }
}

// ---------------------------------------------------------------------------
// Kernel D2 (gcn_b): h2 = conn @ t2 + b2
// ---------------------------------------------------------------------------
__global__ __launch_bounds__(512) void gcn_b(
    const float* __restrict__ conn, const ushort_t* __restrict__ t2tg,
    const float* __restrict__ b2, float* __restrict__ h2out)
{
    __shared__ __align__(16) char cbf[16384];
    const int tid = threadIdx.x;
    const int lane = tid & 63;
    const int w = tid >> 6;
    const int b = blockIdx.x >> 1;
    const int half = blockIdx.x & 1;
    const float* cb = conn + (size_t)b * 16384 + half * 64 * 128;

#pragma unroll
    for (int it = 0; it < 16; ++it) {
        int idx = it * 512 + tid;
        int r = idx >> 7, cc = idx & 127;
        int off = (r * 256 + cc * 2) ^ ((r & 7) << 4);
        *(ushort_t*)(cbf + off) = f2bf(cb[idx]);
    }
    __syncthreads();

    const int wm = w >> 2, wn = w & 3;
    const int fBase = wn * 16;
    f32x4 acc[2];
    const f32x4 zero4 = {0.f, 0.f, 0.f, 0.f};
    acc[0] = zero4; acc[1] = zero4;
    const char* tbase = (const char*)t2tg + (size_t)b * 16384;
#pragma unroll
    for (int ks = 0; ks < 4; ++ks) {
        const bf16x8 bfrag = *(const bf16x8*)(tbase +
            (fBase + (lane & 15)) * 256 + ks * 64 + ((lane >> 4) << 4));
#pragma unroll
        for (int mi = 0; mi < 2; ++mi) {
            int R = wm * 32 + mi * 16 + (lane & 15);
            int off = (R * 256 + ks * 64 + ((lane >> 4) << 4)) ^ ((R & 7) << 4);
            bf16x8 afrag = *(const bf16x8*)(cbf + off);
            acc[mi] = __builtin_amdgcn_mfma_f32_16x16x32_bf16(afrag, bfrag, acc[mi], 0, 0, 0);
        }
    }
    float bias2 = b2[fBase + (lane & 15)];
    float* hb = h2out + (size_t)b * 8192;
#pragma unroll
    for (int mi = 0; mi < 2; ++mi)
#pragma unroll
        for (int r = 0; r < 4; ++r) {
            int i = half * 64 + wm * 32 + mi * 16 + (lane >> 4) * 4 + r;
            hb[i * 64 + fBase + (lane & 15)] = acc[mi][r] + bias2;
        }
}

// ---------------------------------------------------------------------------
// Kernel E: attention (sequential tasks, no spills)
// ---------------------------------------------------------------------------
__global__ __launch_bounds__(256) void attn_kernel(
    const float* __restrict__ h2, const float* __restrict__ Wq,
    const float* __restrict__ bq, const float* __restrict__ Wk,
    const float* __restrict__ bk, const float* __restrict__ Wv,
    const float* __restrict__ bv, const float* __restrict__ Wo,
    const float* __restrict__ bo, float* __restrict__ gf)
{
    __shared__ float h2T[64 * 130];
    __shared__ __align__(16) ushort_t kbf[128 * 64];
    __shared__ __align__(16) ushort_t vbf[128 * 64];
    __shared__ float osm[64 * 64];
    const int tid = threadIdx.x;
    const int b = blockIdx.x >> 1;
    const int half = blockIdx.x & 1;
    const float* h2b = h2 + (size_t)b * 8192;

    for (int idx = tid; idx < 8192; idx += 256) {
        int i = idx >> 6, e = idx & 63;
        h2T[e * 130 + i] = h2b[idx];
    }
    __syncthreads();
    for (int idx = tid; idx < 8192; idx += 256) {
        int i = idx >> 6, f = idx & 63;
        float ak = bk[f], av = bv[f];
        for (int e = 0; e < 64; ++e) {
            float h = h2T[e * 130 + i];
            ak += h * Wk[e * 64 + f];
            av += h * Wv[e * 64 + f];
        }
        kbf[idx] = f2bf(ak);
        vbf[idx] = f2bf(av);
    }
    __syncthreads();
    const float rs = 0.35355339059327373f;
    for (int it = 0; it < 2; ++it) {
        int task = tid + it * 256;
        int il = task & 63;
        int hb8 = (task >> 6) * 8;
        int i = half * 64 + il;
        float q[8];
#pragma unroll
        for (int d = 0; d < 8; ++d) q[d] = bq[hb8 + d];
        for (int e = 0; e < 64; ++e) {
            float hv = h2T[e * 130 + i];
            const float* wr = Wq + e * 64 + hb8;
#pragma unroll
            for (int d = 0; d < 8; ++d) q[d] += hv * wr[d];
        }
        float m = -3.0e38f, l = 0.0f;
        float o[8] = {0, 0, 0, 0, 0, 0, 0, 0};
        for (int j = 0; j < 128; ++j) {
            u16x8 kv = *(const u16x8*)(kbf + j * 64 + hb8);
            float s = 0.0f;
#pragma unroll
            for (int d = 0; d < 8; ++d) s += q[d] * bf2f(kv[d]);
            s *= rs;
            float mn = fmaxf(m, s);
            float cold = __expf(m - mn);
            float ce = __expf(s - mn);
            l = l * cold + ce;
            u16x8 vv = *(const u16x8*)(vbf + j * 64 + hb8);
#pragma unroll
            for (int d = 0; d < 8; ++d) o[d] = o[d] * cold + ce * bf2f(vv[d]);
            m = mn;
        }
        float inv = 1.0f / l;
#pragma unroll
        for (int d = 0; d < 8; ++d) osm[il * 64 + hb8 + d] = o[d] * inv;
    }
    __syncthreads();
    for (int idx = tid; idx < 4096; idx += 256) {
        int il = idx >> 6, f = idx & 63;
        float acc = bo[f];
        const float* orow = osm + il * 64;
        for (int e = 0; e < 64; ++e) acc += orow[e] * Wo[e * 64 + f];
        gf[(size_t)b * 8192 + (size_t)(half * 64 + il) * 64 + f] = acc;
    }
}

// ---------------------------------------------------------------------------
extern "C" void kernel_launch(void* const* d_in, const int* in_sizes, int n_in,
                              void* d_out, int out_size, void* d_ws, size_t ws_size,
                              hipStream_t stream)
{
    (void)in_sizes; (void)n_in; (void)out_size;
    const float* x   = (const float*)d_in[0];
    const float* emb = (const float*)d_in[1];
    const float* W1  = (const float*)d_in[2];
    const float* b1  = (const float*)d_in[3];
    const float* W2  = (const float*)d_in[4];
    const float* b2  = (const float*)d_in[5];
    const float* Wq  = (const float*)d_in[6];
    const float* bq  = (const float*)d_in[7];
    const float* Wk  = (const float*)d_in[8];
    const float* bk  = (const float*)d_in[9];
    const float* Wv  = (const float*)d_in[10];
    const float* bv  = (const float*)d_in[11];
    const float* Wo  = (const float*)d_in[12];
    const float* bo  = (const float*)d_in[13];

    float* out  = (float*)d_out;
    float* conn = out;                    // 128*128*128
    float* gf   = out + 2097152;          // 128*128*64
    float* h2   = out + 3145728;          // 128*128*64

    char* ws = (char*)d_ws;
    ushort_t* nwT  = (ushort_t*)ws;                 // 32KB
    ushort_t* w2t  = (ushort_t*)(ws + 32768);       // 16KB
    ushort_t* t2tg = (ushort_t*)(ws + 49152);       // 2MB
    float2* twg    = (float2*)(ws + 49152 + 2097152);   // 16KB (2047 float2)
    char* zbase = ws + 49152 + 2097152 + 16384;
    size_t reserved = 49152 + 2097152 + 16384;
    size_t avail = (ws_size > reserved) ? (ws_size - reserved) : 0;
    int nb = (int)(avail / 1048576);
    if (nb < 1) nb = 1;
    if (nb > 128) nb = 128;

    twinit_kernel<<<8, 256, 0, stream>>>(twg);
    for (int b0 = 0; b0 < 128; b0 += nb) {
        int cur = (nb < 128 - b0) ? nb : (128 - b0);
        ushort_t* zre = (ushort_t*)zbase;
        ushort_t* zim = zre + (size_t)cur * 128 * FFT_N;
        hilbert_kernel<<<cur * 32, 256, 0, stream>>>(x, zre, zim, twg, b0);
        gram_kernel<<<cur * 2, 512, 0, stream>>>(zre, zim, conn, b0);
    }
    prep_kernel<<<18, 256, 0, stream>>>(emb, W1, W2, nwT, w2t);
    gcn_a<<<256, 512, 0, stream>>>(conn, nwT, w2t, b1, t2tg);
    gcn_b<<<256, 512, 0, stream>>>(conn, t2tg, b2, h2);
    attn_kernel<<<256, 256, 0, stream>>>(h2, Wq, bq, Wk, bk, Wv, bv, Wo, bo, gf);
}

// Round 7
// 237.131 us; speedup vs baseline: 1.3235x; 1.3235x over previous
//
#include <hip/hip_runtime.h>
#include <cstdint>
#include <cstddef>

typedef unsigned short ushort_t;
typedef __bf16 bf16x8 __attribute__((ext_vector_type(8)));
typedef float f32x4 __attribute__((ext_vector_type(4)));
typedef unsigned short u16x8 __attribute__((ext_vector_type(8)));
typedef short s16x8 __attribute__((ext_vector_type(8)));

__device__ __forceinline__ ushort_t f2bf(float f) {
    unsigned u = __builtin_bit_cast(unsigned, f);
    unsigned r = (u + 0x7FFFu + ((u >> 16) & 1u)) >> 16;
    return (ushort_t)r;
}
__device__ __forceinline__ float bf2f(ushort_t h) {
    unsigned u = ((unsigned)h) << 16;
    return __builtin_bit_cast(float, u);
}

#define FFT_N 2048
__device__ __forceinline__ int PADi(int i) { return i + (i >> 4); }

__device__ __forceinline__ float2 cmul(float2 u, float2 w) {
    return make_float2(u.x * w.x - u.y * w.y, u.x * w.y + u.y * w.x);
}
__device__ __forceinline__ float2 cadd(float2 a, float2 b) { return make_float2(a.x + b.x, a.y + b.y); }
__device__ __forceinline__ float2 csub(float2 a, float2 b) { return make_float2(a.x - b.x, a.y - b.y); }

// DIF radix-4 with precomputed (w, w^2, w^3); slot placement with branch
// 1<->2 swap -- math verbatim from verified round-4 dif4.
__device__ __forceinline__ void dif4t(float2* v, float2 w, float2 w2, float2 w3) {
    float2 t0 = cadd(v[0], v[2]);
    float2 t1 = csub(v[0], v[2]);
    float2 t2 = cadd(v[1], v[3]);
    float2 t3 = csub(v[1], v[3]);
    v[0] = cadd(t0, t2);
    v[1] = cmul(csub(t0, t2), w2);
    float2 b1 = make_float2(t1.x + t3.y, t1.y - t3.x);
    v[2] = cmul(b1, w);
    float2 b3 = make_float2(t1.x - t3.y, t1.y + t3.x);
    v[3] = cmul(b3, w3);
}

// DIT radix-4 with precomputed (w, w^2, w^3); natural slot placement --
// math verbatim from verified round-4 dit4 (v1*w^2, v2*w, v3*w^3).
__device__ __forceinline__ void dit4t(float2* v, float2 w, float2 w2, float2 w3) {
    float2 t1 = cmul(v[1], w2);
    float2 t2 = cmul(v[2], w);
    float2 t3 = cmul(v[3], w3);
    float2 sA = cadd(v[0], t1);
    float2 sB = csub(v[0], t1);
    float2 sC = cadd(t2, t3);
    float2 u  = csub(t2, t3);
    v[0] = cadd(sA, sC);
    v[1] = make_float2(sB.x + u.y, sB.y - u.x);
    v[2] = csub(sA, sC);
    v[3] = make_float2(sB.x - u.y, sB.y + u.x);
}

// ---------------------------------------------------------------------------
// twiddle init: triplets (w,w^2,w^3) for level tables (341 entries) + T11.
// twg layout: [0..1023) = 341 triplets; [1023..2047) = T11 singles.
// ---------------------------------------------------------------------------
__global__ __launch_bounds__(256) void twinit_kernel(float2* __restrict__ twg)
{
    int idx = blockIdx.x * 256 + threadIdx.x;
    if (idx >= 1365) return;
    float ang;
    if (idx < 341) {
        int m, p;
        if (idx >= 85)      { m = 4; p = idx - 85; }
        else if (idx >= 21) { m = 3; p = idx - 21; }
        else if (idx >= 5)  { m = 2; p = idx - 5; }
        else if (idx >= 1)  { m = 1; p = idx - 1; }
        else                { m = 0; p = 0; }
        ang = -6.28318530717958647692f * (float)p / (float)(4 << (2 * m));
        float s, co;
        __sincosf(ang, &s, &co);
        float2 w = make_float2(co, s);
        float2 w2 = make_float2(w.x * w.x - w.y * w.y, 2.0f * w.x * w.y);
        float2 w3 = cmul(w2, w);
        twg[idx * 3]     = w;
        twg[idx * 3 + 1] = w2;
        twg[idx * 3 + 2] = w3;
    } else {
        ang = -3.14159265358979323846f * (float)(idx - 341) / 1024.0f;
        float s, co;
        __sincosf(ang, &s, &co);
        twg[1023 + (idx - 341)] = make_float2(co, s);
    }
}

// ---------------------------------------------------------------------------
// Kernel A: Hilbert -> unit-phasor z. 4 rows per block (2 packed row-pairs),
// 128 threads per packed FFT. P = x0 + i*x1 -> Z = DIF-fft(P) (bitrev order)
// -> conj(Q) where Q = -i*Z (k in [1,1023]), 0 (k=0,1024), +i*Z (k>=1025)
// -> w = DIT-fft -> H0 = w.x, H1 = -w.y -> z_j = norm(N*x_j + i*H_j).
// x re-loaded in the final pass (L3-resident) to keep VGPR < 70 (no spills).
// ---------------------------------------------------------------------------
__global__ __launch_bounds__(256) void hilbert_kernel(
    const float* __restrict__ x, ushort_t* __restrict__ zre,
    ushort_t* __restrict__ zim, const float2* __restrict__ twg, int b0)
{
    __shared__ float2 cA[2][2176];
    const int tid = threadIdx.x;
    const int pl = tid >> 7;                     // packed-pair slot in block
    const int t = tid & 127;
    const int pairIdx = blockIdx.x * 2 + pl;     // local row-pair in chunk
    const int row0 = pairIdx * 2;                // local rows row0, row0+1
    const size_t grow = (size_t)(b0 * 128) + row0;
    const float* x0r = x + grow * FFT_N;
    const float* x1r = x0r + FFT_N;
    float2* c = cA[pl];
    const float2* trip = twg;                    // 341 triplets
    const float2* T11  = twg + 1023;             // 1024 singles
    const float2* tb1t = trip + 3;               // level bases *3
    const float2* tb2t = trip + 15;
    const float2* tb3t = trip + 63;
    const float2* tb4t = trip + 255;
    const float2 one = make_float2(1.0f, 0.0f);

    // ---- DIF pass 1: load packed, r2 (T11), dif4 m=4 (tb4 triplet) ----
#pragma unroll
    for (int it = 0; it < 2; ++it) {
        int i = t + it * 128;                    // [0,256)
        float2 v[4][2];
#pragma unroll
        for (int a = 0; a < 4; ++a) {
            int n = i + 256 * a;
            float2 Pn = make_float2(x0r[n], x1r[n]);
            float2 Pm = make_float2(x0r[n + 1024], x1r[n + 1024]);
            float2 w = T11[n];
            v[a][0] = cadd(Pn, Pm);
            v[a][1] = cmul(csub(Pn, Pm), w);
        }
        float2 w4 = tb4t[i * 3], w42 = tb4t[i * 3 + 1], w43 = tb4t[i * 3 + 2];
#pragma unroll
        for (int cc = 0; cc < 2; ++cc) {
            float2 u[4];
#pragma unroll
            for (int a = 0; a < 4; ++a) u[a] = v[a][cc];
            dif4t(u, w4, w42, w43);
            int base = PADi(i) + 1088 * cc;
#pragma unroll
            for (int s = 0; s < 4; ++s) c[base + 272 * s] = u[s];
        }
    }
    __syncthreads();

    // ---- DIF pass 2: m=3 (tb3[p+16a]), m=2 (tb2[p]) ----
    {
        int p = t & 15, g = t >> 4;
        int base = 272 * g + p;
        float2 v[4][4];
#pragma unroll
        for (int a = 0; a < 4; ++a)
#pragma unroll
            for (int b = 0; b < 4; ++b) v[a][b] = c[base + 17 * a + 68 * b];
#pragma unroll
        for (int a = 0; a < 4; ++a) {
            int j = (p + 16 * a) * 3;
            float2 u[4];
#pragma unroll
            for (int b = 0; b < 4; ++b) u[b] = v[a][b];
            dif4t(u, tb3t[j], tb3t[j + 1], tb3t[j + 2]);
#pragma unroll
            for (int b = 0; b < 4; ++b) v[a][b] = u[b];
        }
        float2 w2p = tb2t[p * 3], w2p2 = tb2t[p * 3 + 1], w2p3 = tb2t[p * 3 + 2];
#pragma unroll
        for (int b = 0; b < 4; ++b) {
            float2 u[4];
#pragma unroll
            for (int a = 0; a < 4; ++a) u[a] = v[a][b];
            dif4t(u, w2p, w2p2, w2p3);
#pragma unroll
            for (int a = 0; a < 4; ++a) v[a][b] = u[a];
        }
#pragma unroll
        for (int a = 0; a < 4; ++a)
#pragma unroll
            for (int b = 0; b < 4; ++b) c[base + 17 * a + 68 * b] = v[a][b];
    }
    __syncthreads();

    // ---- DIF pass 3: m=1 (tb1[a]), m=0 (w=1); fused Q-mask (sign/swap) ----
    {
        int g = t;
        int base = 17 * g;
        float2 v[4][4];                          // [b][a], idx = 16g+4b+a
#pragma unroll
        for (int b = 0; b < 4; ++b)
#pragma unroll
            for (int a = 0; a < 4; ++a) v[b][a] = c[base + 4 * b + a];
#pragma unroll
        for (int a = 0; a < 4; ++a) {
            int j = a * 3;
            float2 u[4];
#pragma unroll
            for (int b = 0; b < 4; ++b) u[b] = v[b][a];
            dif4t(u, tb1t[j], tb1t[j + 1], tb1t[j + 2]);
#pragma unroll
            for (int b = 0; b < 4; ++b) v[b][a] = u[b];
        }
#pragma unroll
        for (int b = 0; b < 4; ++b) dif4t(v[b], one, one, one);
        // conj(Q): k in [1,1023] -> (v.y, v.x); k in {0,1024} -> 0;
        //          k >= 1025    -> (-v.y, -v.x)
#pragma unroll
        for (int b = 0; b < 4; ++b)
#pragma unroll
            for (int a = 0; a < 4; ++a) {
                int idx = 16 * g + 4 * b + a;
                int k = __brev((unsigned)idx) >> 21;
                float s = (k == 0 || k == 1024) ? 0.0f : (k < 1024 ? 1.0f : -1.0f);
                float2 w = v[b][a];
                c[base + 4 * b + a] = make_float2(s * w.y, s * w.x);
            }
    }
    __syncthreads();

    // ---- DIT pass 1: m=0 (w=1), m=1 (tb1[a]) ----
    {
        int g = t;
        int base = 17 * g;
        float2 v[4][4];
#pragma unroll
        for (int b = 0; b < 4; ++b)
#pragma unroll
            for (int a = 0; a < 4; ++a) v[b][a] = c[base + 4 * b + a];
#pragma unroll
        for (int b = 0; b < 4; ++b) dit4t(v[b], one, one, one);
#pragma unroll
        for (int a = 0; a < 4; ++a) {
            int j = a * 3;
            float2 u[4];
#pragma unroll
            for (int b = 0; b < 4; ++b) u[b] = v[b][a];
            dit4t(u, tb1t[j], tb1t[j + 1], tb1t[j + 2]);
#pragma unroll
            for (int b = 0; b < 4; ++b) v[b][a] = u[b];
        }
#pragma unroll
        for (int b = 0; b < 4; ++b)
#pragma unroll
            for (int a = 0; a < 4; ++a) c[base + 4 * b + a] = v[b][a];
    }
    __syncthreads();

    // ---- DIT pass 2: m=2 (tb2[p]), m=3 (tb3[p+16a]) ----
    {
        int p = t & 15, g = t >> 4;
        int base = 272 * g + p;
        float2 v[4][4];
#pragma unroll
        for (int a = 0; a < 4; ++a)
#pragma unroll
            for (int b = 0; b < 4; ++b) v[a][b] = c[base + 17 * a + 68 * b];
        float2 w2p = tb2t[p * 3], w2p2 = tb2t[p * 3 + 1], w2p3 = tb2t[p * 3 + 2];
#pragma unroll
        for (int b = 0; b < 4; ++b) {
            float2 u[4];
#pragma unroll
            for (int a = 0; a < 4; ++a) u[a] = v[a][b];
            dit4t(u, w2p, w2p2, w2p3);
#pragma unroll
            for (int a = 0; a < 4; ++a) v[a][b] = u[a];
        }
#pragma unroll
        for (int a = 0; a < 4; ++a) {
            int j = (p + 16 * a) * 3;
            float2 u[4];
#pragma unroll
            for (int b = 0; b < 4; ++b) u[b] = v[a][b];
            dit4t(u, tb3t[j], tb3t[j + 1], tb3t[j + 2]);
#pragma unroll
            for (int b = 0; b < 4; ++b) v[a][b] = u[b];
        }
#pragma unroll
        for (int a = 0; a < 4; ++a)
#pragma unroll
            for (int b = 0; b < 4; ++b) c[base + 17 * a + 68 * b] = v[a][b];
    }
    __syncthreads();

    // ---- DIT pass 3: m=4 (tb4[i]), r2 (T11); re-load x, unpack, normalize ----
    ushort_t* zr0 = zre + (size_t)row0 * FFT_N;
    ushort_t* zi0 = zim + (size_t)row0 * FFT_N;
    ushort_t* zr1 = zr0 + FFT_N;
    ushort_t* zi1 = zi0 + FFT_N;
#pragma unroll
    for (int it = 0; it < 2; ++it) {
        int i = t + it * 128;
        float2 v[4][2];
#pragma unroll
        for (int cc = 0; cc < 2; ++cc) {
            int base = PADi(i) + 1088 * cc;
#pragma unroll
            for (int a = 0; a < 4; ++a) v[a][cc] = c[base + 272 * a];
        }
        float2 w4 = tb4t[i * 3], w42 = tb4t[i * 3 + 1], w43 = tb4t[i * 3 + 2];
#pragma unroll
        for (int cc = 0; cc < 2; ++cc) {
            float2 u[4];
#pragma unroll
            for (int a = 0; a < 4; ++a) u[a] = v[a][cc];
            dit4t(u, w4, w42, w43);
#pragma unroll
            for (int a = 0; a < 4; ++a) v[a][cc] = u[a];
        }
#pragma unroll
        for (int a = 0; a < 4; ++a) {
            float2 wa = T11[i + 256 * a];
            float2 tt = cmul(v[a][1], wa);
            float2 e0 = cadd(v[a][0], tt);
            float2 e1 = csub(v[a][0], tt);
            int n0 = i + 256 * a;
#pragma unroll
            for (int h = 0; h < 2; ++h) {
                float2 w = h ? e1 : e0;
                int n = n0 + 1024 * h;
                float a0 = 2048.0f * x0r[n];
                float a1 = 2048.0f * x1r[n];
                float H0 = w.x, H1 = -w.y;
                float m0 = a0 * a0 + H0 * H0;
                float m1 = a1 * a1 + H1 * H1;
                float zr, zi;
                if (m0 < 1e-24f) { zr = 1.0f; zi = 0.0f; }
                else { float inv = rsqrtf(m0); zr = a0 * inv; zi = H0 * inv; }
                zr0[n] = f2bf(zr); zi0[n] = f2bf(zi);
                if (m1 < 1e-24f) { zr = 1.0f; zi = 0.0f; }
                else { float inv = rsqrtf(m1); zr = a1 * inv; zi = H1 * inv; }
                zr1[n] = f2bf(zr); zi1[n] = f2bf(zi);
            }
        }
    }
}

// ---------------------------------------------------------------------------
// Kernel B: conn = |Z Z^H|/T (bf16 MFMA), unchanged.
// ---------------------------------------------------------------------------
__global__ __launch_bounds__(512) void gram_kernel(
    const ushort_t* __restrict__ zre, const ushort_t* __restrict__ zim,
    float* __restrict__ out, int b0)
{
    __shared__ __align__(16) char sm[65536];
    const int tid = threadIdx.x;
    const int bl = blockIdx.x;
    const int b_local = bl >> 1;
    const int half = bl & 1;
    const int b = b0 + b_local;
    const int lane = tid & 63;
    const int w = tid >> 6;
    const int wm = w >> 2, wn = w & 3;
    const size_t zbase = (size_t)b_local * 128 * FFT_N;

    f32x4 accR[2][2], accI[2][2];
    const f32x4 zero4 = {0.f, 0.f, 0.f, 0.f};
#pragma unroll
    for (int mi = 0; mi < 2; ++mi)
#pragma unroll
        for (int nj = 0; nj < 2; ++nj) { accR[mi][nj] = zero4; accI[mi][nj] = zero4; }

    auto stage = [&](int kc, int buf) {
        const int kcol = kc * 64;
#pragma unroll
        for (int it = 0; it < 4; ++it) {
            int cid = it * 512 + tid;
            int p = cid >> 10;
            int rem = cid & 1023;
            int r = rem >> 3;
            int g = rem & 7;
            const ushort_t* src = (p ? zim : zre) + zbase + (size_t)r * FFT_N + kcol + g * 8;
            u16x8 v = *(const u16x8*)src;
            int off = (buf << 15) | (p << 14) | (r << 7) | (g << 4);
            off ^= ((r & 7) << 4);
            *(u16x8*)(sm + off) = v;
        }
    };

    stage(0, 0);
    __syncthreads();
    int buf = 0;
    const int mBase = half * 64 + wm * 32;
    const int nBase = wn * 32;
    for (int kc = 0; kc < 32; ++kc) {
        if (kc + 1 < 32) stage(kc + 1, buf ^ 1);
        const char* base = sm + (buf << 15);
#pragma unroll
        for (int ks = 0; ks < 2; ++ks) {
            bf16x8 aRe[2], aIm[2], bRe[2], bIm[2], nRe[2];
#pragma unroll
            for (int mi = 0; mi < 2; ++mi) {
                int R = mBase + mi * 16 + (lane & 15);
                int off = (R << 7) | (ks << 6) | ((lane >> 4) << 4);
                off ^= ((R & 7) << 4);
                aRe[mi] = *(const bf16x8*)(base + off);
                aIm[mi] = *(const bf16x8*)(base + 16384 + off);
                s16x8 t = __builtin_bit_cast(s16x8, aRe[mi]);
                t ^= (short)0x8000;
                nRe[mi] = __builtin_bit_cast(bf16x8, t);
            }
#pragma unroll
            for (int nj = 0; nj < 2; ++nj) {
                int C = nBase + nj * 16 + (lane & 15);
                int off = (C << 7) | (ks << 6) | ((lane >> 4) << 4);
                off ^= ((C & 7) << 4);
                bRe[nj] = *(const bf16x8*)(base + off);
                bIm[nj] = *(const bf16x8*)(base + 16384 + off);
            }
#pragma unroll
            for (int mi = 0; mi < 2; ++mi)
#pragma unroll
                for (int nj = 0; nj < 2; ++nj) {
                    accR[mi][nj] = __builtin_amdgcn_mfma_f32_16x16x32_bf16(aRe[mi], bRe[nj], accR[mi][nj], 0, 0, 0);
                    accR[mi][nj] = __builtin_amdgcn_mfma_f32_16x16x32_bf16(aIm[mi], bIm[nj], accR[mi][nj], 0, 0, 0);
                    accI[mi][nj] = __builtin_amdgcn_mfma_f32_16x16x32_bf16(aIm[mi], bRe[nj], accI[mi][nj], 0, 0, 0);
                    accI[mi][nj] = __builtin_amdgcn_mfma_f32_16x16x32_bf16(nRe[mi], bIm[nj], accI[mi][nj], 0, 0, 0);
                }
        }
        __syncthreads();
        buf ^= 1;
    }
    float* ob = out + (size_t)b * 16384;
#pragma unroll
    for (int mi = 0; mi < 2; ++mi)
#pragma unroll
        for (int nj = 0; nj < 2; ++nj)
#pragma unroll
            for (int r = 0; r < 4; ++r) {
                int i = mBase + mi * 16 + (lane >> 4) * 4 + r;
                int j = nBase + nj * 16 + (lane & 15);
                float re = accR[mi][nj][r], im = accI[mi][nj][r];
                float v = sqrtf(re * re + im * im) * (1.0f / 2048.0f);
                if (i == j) v = 0.0f;
                ob[i * 128 + j] = v;
            }
}

// ---------------------------------------------------------------------------
// Kernel C (prep): nwT[f][j] = bf16(sum_e emb[j][e]*W1[e][f]); w2t = W2^T bf16
// ---------------------------------------------------------------------------
__global__ __launch_bounds__(256) void prep_kernel(
    const float* __restrict__ emb, const float* __restrict__ W1,
    const float* __restrict__ W2, ushort_t* __restrict__ nwT,
    ushort_t* __restrict__ w2t)
{
    const int tid = threadIdx.x;
    const int bid = blockIdx.x;
    if (bid < 16) {
#pragma unroll
        for (int it = 0; it < 4; ++it) {
            int idx = it * 256 + tid;
            int f = bid * 8 + (idx >> 7);
            int j = idx & 127;
            float acc = 0.0f;
            for (int e = 0; e < 64; ++e) acc += emb[j * 64 + e] * W1[e * 128 + f];
            nwT[f * 128 + j] = f2bf(acc);
        }
    } else {
        int base = (bid - 16) * 4096;
#pragma unroll
        for (int it = 0; it < 16; ++it) {
            int idx = base + it * 256 + tid;
            int f = idx >> 7;
            int g = idx & 127;
            w2t[f * 128 + g] = f2bf(W2[g * 64 + f]);
        }
    }
}

// ---------------------------------------------------------------------------
// Kernel D1 (gcn_a): h1 = relu(conn@nodeW1+b1); t2 = h1@W2 (transposed bf16 out)
// ---------------------------------------------------------------------------
__global__ __launch_bounds__(512) void gcn_a(
    const float* __restrict__ conn, const ushort_t* __restrict__ nwT,
    const ushort_t* __restrict__ w2t, const float* __restrict__ b1,
    ushort_t* __restrict__ t2tg)
{
    __shared__ __align__(16) char cbf[16384];
    __shared__ __align__(16) char h1b[16384];
    const int tid = threadIdx.x;
    const int lane = tid & 63;
    const int w = tid >> 6;
    const int b = blockIdx.x >> 1;
    const int half = blockIdx.x & 1;
    const float* cb = conn + (size_t)b * 16384 + half * 64 * 128;

#pragma unroll
    for (int it = 0; it < 16; ++it) {
        int idx = it * 512 + tid;
        int r = idx >> 7, cc = idx & 127;
        int off = (r * 256 + cc * 2) ^ ((r & 7) << 4);
        *(ushort_t*)(cbf + off) = f2bf(cb[idx]);
    }
    __syncthreads();

    const int nBase = w * 16;
    f32x4 acc[4];
    const f32x4 zero4 = {0.f, 0.f, 0.f, 0.f};
#pragma unroll
    for (int mi = 0; mi < 4; ++mi) acc[mi] = zero4;
#pragma unroll
    for (int ks = 0; ks < 4; ++ks) {
        const bf16x8 bfrag = *(const bf16x8*)((const char*)nwT +
            (nBase + (lane & 15)) * 256 + ks * 64 + ((lane >> 4) << 4));
#pragma unroll
        for (int mi = 0; mi < 4; ++mi) {
            int R = mi * 16 + (lane & 15);
            int off = (R * 256 + ks * 64 + ((lane >> 4) << 4)) ^ ((R & 7) << 4);
            bf16x8 afrag = *(const bf16x8*)(cbf + off);
            acc[mi] = __builtin_amdgcn_mfma_f32_16x16x32_bf16(afrag, bfrag, acc[mi], 0, 0, 0);
        }
    }
    float bias1 = b1[nBase + (lane & 15)];
#pragma unroll
    for (int mi = 0; mi < 4; ++mi)
#pragma unroll
        for (int r = 0; r < 4; ++r) {
            int i = mi * 16 + (lane >> 4) * 4 + r;
            float v = fmaxf(acc[mi][r] + bias1, 0.0f);
            int off = (i * 256 + (nBase + (lane & 15)) * 2) ^ ((i & 7) << 4);
            *(ushort_t*)(h1b + off) = f2bf(v);
        }
    __syncthreads();

    const int wm2 = w >> 2, wn2 = w & 3;
    const int f2Base = wn2 * 16;
    f32x4 acc2[2];
    acc2[0] = zero4; acc2[1] = zero4;
#pragma unroll
    for (int ks = 0; ks < 4; ++ks) {
        const bf16x8 bfrag = *(const bf16x8*)((const char*)w2t +
            (f2Base + (lane & 15)) * 256 + ks * 64 + ((lane >> 4) << 4));
#pragma unroll
        for (int mi = 0; mi < 2; ++mi) {
            int R = wm2 * 32 + mi * 16 + (lane & 15);
            int off = (R * 256 + ks * 64 + ((lane >> 4) << 4)) ^ ((R & 7) << 4);
            bf16x8 afrag = *(const bf16x8*)(h1b + off);
            acc2[mi] = __builtin_amdgcn_mfma_f32_16x16x32_bf16(afrag, bfrag, acc2[mi], 0, 0, 0);
        }
    }
    ushort_t* tb = t2tg + (size_t)b * 8192;
#pragma unroll
    for (int mi = 0; mi < 2; ++mi)
#pragma unroll
        for (int r = 0; r < 4; ++r) {
            int i = wm2 * 32 + mi * 16 + (lane >> 4) * 4 + r;
            int f = f2Base + (lane & 15);
            tb[f * 128 + half * 64 + i] = f2bf(acc2[mi][r]);
        }
}

// ---------------------------------------------------------------------------
// Kernel D2 (gcn_b): h2 = conn @ t2 + b2
// ---------------------------------------------------------------------------
__global__ __launch_bounds__(512) void gcn_b(
    const float* __restrict__ conn, const ushort_t* __restrict__ t2tg,
    const float* __restrict__ b2, float* __restrict__ h2out)
{
    __shared__ __align__(16) char cbf[16384];
    const int tid = threadIdx.x;
    const int lane = tid & 63;
    const int w = tid >> 6;
    const int b = blockIdx.x >> 1;
    const int half = blockIdx.x & 1;
    const float* cb = conn + (size_t)b * 16384 + half * 64 * 128;

#pragma unroll
    for (int it = 0; it < 16; ++it) {
        int idx = it * 512 + tid;
        int r = idx >> 7, cc = idx & 127;
        int off = (r * 256 + cc * 2) ^ ((r & 7) << 4);
        *(ushort_t*)(cbf + off) = f2bf(cb[idx]);
    }
    __syncthreads();

    const int wm = w >> 2, wn = w & 3;
    const int fBase = wn * 16;
    f32x4 acc[2];
    const f32x4 zero4 = {0.f, 0.f, 0.f, 0.f};
    acc[0] = zero4; acc[1] = zero4;
    const char* tbase = (const char*)t2tg + (size_t)b * 16384;
#pragma unroll
    for (int ks = 0; ks < 4; ++ks) {
        const bf16x8 bfrag = *(const bf16x8*)(tbase +
            (fBase + (lane & 15)) * 256 + ks * 64 + ((lane >> 4) << 4));
#pragma unroll
        for (int mi = 0; mi < 2; ++mi) {
            int R = wm * 32 + mi * 16 + (lane & 15);
            int off = (R * 256 + ks * 64 + ((lane >> 4) << 4)) ^ ((R & 7) << 4);
            bf16x8 afrag = *(const bf16x8*)(cbf + off);
            acc[mi] = __builtin_amdgcn_mfma_f32_16x16x32_bf16(afrag, bfrag, acc[mi], 0, 0, 0);
        }
    }
    float bias2 = b2[fBase + (lane & 15)];
    float* hb = h2out + (size_t)b * 8192;
#pragma unroll
    for (int mi = 0; mi < 2; ++mi)
#pragma unroll
        for (int r = 0; r < 4; ++r) {
            int i = half * 64 + wm * 32 + mi * 16 + (lane >> 4) * 4 + r;
            hb[i * 64 + fBase + (lane & 15)] = acc[mi][r] + bias2;
        }
}

// ---------------------------------------------------------------------------
// Kernel E: attention (sequential tasks, no spills)
// ---------------------------------------------------------------------------
__global__ __launch_bounds__(256) void attn_kernel(
    const float* __restrict__ h2, const float* __restrict__ Wq,
    const float* __restrict__ bq, const float* __restrict__ Wk,
    const float* __restrict__ bk, const float* __restrict__ Wv,
    const float* __restrict__ bv, const float* __restrict__ Wo,
    const float* __restrict__ bo, float* __restrict__ gf)
{
    __shared__ float h2T[64 * 130];
    __shared__ __align__(16) ushort_t kbf[128 * 64];
    __shared__ __align__(16) ushort_t vbf[128 * 64];
    __shared__ float osm[64 * 64];
    const int tid = threadIdx.x;
    const int b = blockIdx.x >> 1;
    const int half = blockIdx.x & 1;
    const float* h2b = h2 + (size_t)b * 8192;

    for (int idx = tid; idx < 8192; idx += 256) {
        int i = idx >> 6, e = idx & 63;
        h2T[e * 130 + i] = h2b[idx];
    }
    __syncthreads();
    for (int idx = tid; idx < 8192; idx += 256) {
        int i = idx >> 6, f = idx & 63;
        float ak = bk[f], av = bv[f];
        for (int e = 0; e < 64; ++e) {
            float h = h2T[e * 130 + i];
            ak += h * Wk[e * 64 + f];
            av += h * Wv[e * 64 + f];
        }
        kbf[idx] = f2bf(ak);
        vbf[idx] = f2bf(av);
    }
    __syncthreads();
    const float rs = 0.35355339059327373f;
    for (int it = 0; it < 2; ++it) {
        int task = tid + it * 256;
        int il = task & 63;
        int hb8 = (task >> 6) * 8;
        int i = half * 64 + il;
        float q[8];
#pragma unroll
        for (int d = 0; d < 8; ++d) q[d] = bq[hb8 + d];
        for (int e = 0; e < 64; ++e) {
            float hv = h2T[e * 130 + i];
            const float* wr = Wq + e * 64 + hb8;
#pragma unroll
            for (int d = 0; d < 8; ++d) q[d] += hv * wr[d];
        }
        float m = -3.0e38f, l = 0.0f;
        float o[8] = {0, 0, 0, 0, 0, 0, 0, 0};
        for (int j = 0; j < 128; ++j) {
            u16x8 kv = *(const u16x8*)(kbf + j * 64 + hb8);
            float s = 0.0f;
#pragma unroll
            for (int d = 0; d < 8; ++d) s += q[d] * bf2f(kv[d]);
            s *= rs;
            float mn = fmaxf(m, s);
            float cold = __expf(m - mn);
            float ce = __expf(s - mn);
            l = l * cold + ce;
            u16x8 vv = *(const u16x8*)(vbf + j * 64 + hb8);
#pragma unroll
            for (int d = 0; d < 8; ++d) o[d] = o[d] * cold + ce * bf2f(vv[d]);
            m = mn;
        }
        float inv = 1.0f / l;
#pragma unroll
        for (int d = 0; d < 8; ++d) osm[il * 64 + hb8 + d] = o[d] * inv;
    }
    __syncthreads();
    for (int idx = tid; idx < 4096; idx += 256) {
        int il = idx >> 6, f = idx & 63;
        float acc = bo[f];
        const float* orow = osm + il * 64;
        for (int e = 0; e < 64; ++e) acc += orow[e] * Wo[e * 64 + f];
        gf[(size_t)b * 8192 + (size_t)(half * 64 + il) * 64 + f] = acc;
    }
}

// ---------------------------------------------------------------------------
extern "C" void kernel_launch(void* const* d_in, const int* in_sizes, int n_in,
                              void* d_out, int out_size, void* d_ws, size_t ws_size,
                              hipStream_t stream)
{
    (void)in_sizes; (void)n_in; (void)out_size;
    const float* x   = (const float*)d_in[0];
    const float* emb = (const float*)d_in[1];
    const float* W1  = (const float*)d_in[2];
    const float* b1  = (const float*)d_in[3];
    const float* W2  = (const float*)d_in[4];
    const float* b2  = (const float*)d_in[5];
    const float* Wq  = (const float*)d_in[6];
    const float* bq  = (const float*)d_in[7];
    const float* Wk  = (const float*)d_in[8];
    const float* bk  = (const float*)d_in[9];
    const float* Wv  = (const float*)d_in[10];
    const float* bv  = (const float*)d_in[11];
    const float* Wo  = (const float*)d_in[12];
    const float* bo  = (const float*)d_in[13];

    float* out  = (float*)d_out;
    float* conn = out;                    // 128*128*128
    float* gf   = out + 2097152;          // 128*128*64
    float* h2   = out + 3145728;          // 128*128*64

    char* ws = (char*)d_ws;
    ushort_t* nwT  = (ushort_t*)ws;                 // 32KB
    ushort_t* w2t  = (ushort_t*)(ws + 32768);       // 16KB
    ushort_t* t2tg = (ushort_t*)(ws + 49152);       // 2MB
    float2* twg    = (float2*)(ws + 49152 + 2097152);   // 16KB (2047 float2)
    char* zbase = ws + 49152 + 2097152 + 16384;
    size_t reserved = 49152 + 2097152 + 16384;
    size_t avail = (ws_size > reserved) ? (ws_size - reserved) : 0;
    int nb = (int)(avail / 1048576);
    if (nb < 1) nb = 1;
    if (nb > 128) nb = 128;

    twinit_kernel<<<8, 256, 0, stream>>>(twg);
    for (int b0 = 0; b0 < 128; b0 += nb) {
        int cur = (nb < 128 - b0) ? nb : (128 - b0);
        ushort_t* zre = (ushort_t*)zbase;
        ushort_t* zim = zre + (size_t)cur * 128 * FFT_N;
        hilbert_kernel<<<cur * 32, 256, 0, stream>>>(x, zre, zim, twg, b0);
        gram_kernel<<<cur * 2, 512, 0, stream>>>(zre, zim, conn, b0);
    }
    prep_kernel<<<18, 256, 0, stream>>>(emb, W1, W2, nwT, w2t);
    gcn_a<<<256, 512, 0, stream>>>(conn, nwT, w2t, b1, t2tg);
    gcn_b<<<256, 512, 0, stream>>>(conn, t2tg, b2, h2);
    attn_kernel<<<256, 256, 0, stream>>>(h2, Wq, bq, Wk, bk, Wv, bv, Wo, bo, gf);
}